// Round 1
// baseline (339.718 us; speedup 1.0000x reference)
//
#include <hip/hip_runtime.h>
#include <math.h>

#define TOKENS    1024
#define IN_W      512
#define BLOCK_H   256
#define OUT_W     512
#define N_EXPERTS 64
#define TOPK      2

// ---------------------------------------------------------------------------
// Kernel 1: routing. One block (1 wave, 64 threads) per token; thread e
// computes the two 512-length dots for expert e, then lane 0 does top-2 +
// softmax. Writes expert indices + scores to workspace.
// ---------------------------------------------------------------------------
__global__ __launch_bounds__(64) void routing_kernel(
    const float* __restrict__ x, const float* __restrict__ noise,
    const float* __restrict__ mixer, const float* __restrict__ noisec,
    int* __restrict__ eidx, float* __restrict__ esc)
{
    __shared__ float xs[IN_W];
    __shared__ float hs[N_EXPERTS];
    const int t = blockIdx.x;
    const int e = threadIdx.x;

    // stage x row (512 f32 = 128 float4) into LDS
    const float4* xrow = (const float4*)(x + (size_t)t * IN_W);
    float4* xs4 = (float4*)xs;
    for (int i = e; i < IN_W / 4; i += 64) xs4[i] = xrow[i];
    __syncthreads();

    float accm = 0.f, accn = 0.f;
    #pragma unroll 8
    for (int i = 0; i < IN_W; ++i) {
        const float xv = xs[i];
        accm = fmaf(xv, mixer [i * N_EXPERTS + e], accm);  // coalesced across e
        accn = fmaf(xv, noisec[i * N_EXPERTS + e], accn);
    }
    // softplus(accn) = max(x,0) + log1p(exp(-|x|))  (== logaddexp(x, 0))
    const float sp = fmaxf(accn, 0.f) + log1pf(expf(-fabsf(accn)));
    hs[e] = accm + noise[t * N_EXPERTS + e] * sp;
    __syncthreads();

    if (e == 0) {
        float b0 = -INFINITY, b1 = -INFINITY;
        int i0 = 0, i1 = 0;
        for (int i = 0; i < N_EXPERTS; ++i) {
            const float v = hs[i];
            if (v > b0)      { b1 = b0; i1 = i0; b0 = v; i0 = i; }  // strict >: stable ties
            else if (v > b1) { b1 = v; i1 = i; }
        }
        // softmax over (b0, b1), b0 >= b1
        const float z   = expf(b1 - b0);
        const float inv = 1.f / (1.f + z);
        eidx[t * 2 + 0] = i0;  esc[t * 2 + 0] = inv;
        eidx[t * 2 + 1] = i1;  esc[t * 2 + 1] = z * inv;
    }
}

// ---------------------------------------------------------------------------
// Kernel 2: expert FFN. One block (256 threads) per (token, k) slot.
// Phase 1: v[h] = relu(x . w1[:,h] + b1[h])   (thread h, coalesced w1 reads)
// Phase 2: out[o] += score * (v . w2[:,o] + b2[o])  (thread handles o, o+256)
// Accumulation across the K=2 slots via fp32 atomicAdd (out pre-zeroed).
// ---------------------------------------------------------------------------
__global__ __launch_bounds__(256) void expert_kernel(
    const float* __restrict__ x,
    const float* __restrict__ w1s, const float* __restrict__ b1s,
    const float* __restrict__ w2s, const float* __restrict__ b2s,
    const int* __restrict__ eidx, const float* __restrict__ esc,
    float* __restrict__ out)
{
    __shared__ float xs[IN_W];
    __shared__ float vs[BLOCK_H];
    const int slot = blockIdx.x;
    const int t    = slot >> 1;
    const int e    = eidx[slot];
    const float s  = esc[slot];
    const int tid  = threadIdx.x;

    xs[tid]       = x[(size_t)t * IN_W + tid];
    xs[tid + 256] = x[(size_t)t * IN_W + tid + 256];
    __syncthreads();

    // phase 1: hidden activation for column tid
    const float* w1 = w1s + (size_t)e * IN_W * BLOCK_H;
    float acc = 0.f;
    #pragma unroll 8
    for (int i = 0; i < IN_W; ++i)
        acc = fmaf(xs[i], w1[i * BLOCK_H + tid], acc);   // coalesced across tid
    acc += b1s[e * BLOCK_H + tid];
    vs[tid] = fmaxf(acc, 0.f);
    __syncthreads();

    // phase 2: two output columns per thread
    const float* w2 = w2s + (size_t)e * BLOCK_H * OUT_W;
    float a0 = 0.f, a1 = 0.f;
    #pragma unroll 8
    for (int h = 0; h < BLOCK_H; ++h) {
        const float v = vs[h];
        a0 = fmaf(v, w2[h * OUT_W + tid],       a0);     // coalesced across tid
        a1 = fmaf(v, w2[h * OUT_W + tid + 256], a1);
    }
    a0 = (a0 + b2s[e * OUT_W + tid])       * s;
    a1 = (a1 + b2s[e * OUT_W + tid + 256]) * s;
    atomicAdd(&out[(size_t)t * OUT_W + tid],       a0);
    atomicAdd(&out[(size_t)t * OUT_W + tid + 256], a1);
}

extern "C" void kernel_launch(void* const* d_in, const int* in_sizes, int n_in,
                              void* d_out, int out_size, void* d_ws, size_t ws_size,
                              hipStream_t stream) {
    const float* x      = (const float*)d_in[0];
    const float* noise  = (const float*)d_in[1];
    const float* w1s    = (const float*)d_in[2];
    const float* b1s    = (const float*)d_in[3];
    const float* w2s    = (const float*)d_in[4];
    const float* b2s    = (const float*)d_in[5];
    const float* mixer  = (const float*)d_in[6];
    const float* noisec = (const float*)d_in[7];
    // d_in[8] is k == 2 (compile-time TOPK)

    float* out = (float*)d_out;

    // workspace: [2048 int eidx][2048 float esc]
    int*   eidx = (int*)d_ws;
    float* esc  = (float*)((char*)d_ws + TOKENS * TOPK * sizeof(int));

    hipMemsetAsync(d_out, 0, (size_t)out_size * sizeof(float), stream);

    routing_kernel<<<TOKENS, 64, 0, stream>>>(x, noise, mixer, noisec, eidx, esc);
    expert_kernel<<<TOKENS * TOPK, 256, 0, stream>>>(x, w1s, b1s, w2s, b2s,
                                                     eidx, esc, out);
}

// Round 3
// 261.716 us; speedup vs baseline: 1.2980x; 1.2980x over previous
//
#include <hip/hip_runtime.h>
#include <math.h>

#define TOKENS    1024
#define IN_W      512
#define BLOCK_H   256
#define OUT_W     512
#define N_EXPERTS 64
#define TOPK      2
#define NSLOTS    (TOKENS * TOPK)
#define LIST_CAP  128          // expected ~32 tokens/expert (sigma ~5.6); 128 = +17 sigma
#define CHUNK     16           // tokens per fused block pass
#define XPAD      520          // 512 + 8 floats; row stride 2080 B (16B-aligned)
#define VPAD      264          // 256 + 8

// ---------------------------------------------------------------------------
// Kernel 0: routing. 128 blocks x 256 threads; block handles 8 tokens.
// ---------------------------------------------------------------------------
__global__ __launch_bounds__(256) void routing_kernel(
    const float* __restrict__ x, const float* __restrict__ noise,
    const float* __restrict__ mixer, const float* __restrict__ noisec,
    int* __restrict__ eidx, float* __restrict__ esc)
{
    __shared__ float xs[8 * 512];
    __shared__ float hs[8 * 64];
    const int blk = blockIdx.x;
    const int tid = threadIdx.x;
    const int e   = tid & 63;
    const int tg  = tid >> 6;

    const float4* x4 = (const float4*)x;
    float4* xs4 = (float4*)xs;
    for (int idx = tid; idx < 8 * 128; idx += 256)
        xs4[idx] = x4[(size_t)blk * 8 * 128 + idx];
    __syncthreads();

    float am0 = 0.f, an0 = 0.f, am1 = 0.f, an1 = 0.f;
    #pragma unroll 8
    for (int i = 0; i < IN_W; ++i) {
        const float m  = mixer [i * N_EXPERTS + e];
        const float n  = noisec[i * N_EXPERTS + e];
        const float x0 = xs[tg * 512 + i];
        const float x1 = xs[(tg + 4) * 512 + i];
        am0 = fmaf(x0, m, am0);  an0 = fmaf(x0, n, an0);
        am1 = fmaf(x1, m, am1);  an1 = fmaf(x1, n, an1);
    }
    const int t0 = blk * 8 + tg, t1 = t0 + 4;
    const float sp0 = fmaxf(an0, 0.f) + log1pf(expf(-fabsf(an0)));
    const float sp1 = fmaxf(an1, 0.f) + log1pf(expf(-fabsf(an1)));
    hs[tg * 64 + e]       = am0 + noise[t0 * N_EXPERTS + e] * sp0;
    hs[(tg + 4) * 64 + e] = am1 + noise[t1 * N_EXPERTS + e] * sp1;
    __syncthreads();

    if (tid < 8) {
        const float* h = hs + tid * 64;
        float b0 = -INFINITY, b1 = -INFINITY;
        int i0 = 0, i1 = 0;
        for (int i = 0; i < N_EXPERTS; ++i) {
            const float v = h[i];
            if (v > b0)      { b1 = b0; i1 = i0; b0 = v; i0 = i; }  // strict >: stable ties
            else if (v > b1) { b1 = v; i1 = i; }
        }
        const float z   = expf(b1 - b0);
        const float inv = 1.f / (1.f + z);
        const int t = blk * 8 + tid;
        eidx[t * 2 + 0] = i0;  esc[t * 2 + 0] = inv;
        eidx[t * 2 + 1] = i1;  esc[t * 2 + 1] = z * inv;
    }
}

// ---------------------------------------------------------------------------
// Kernel 1: compaction — per-expert slot lists.
// ---------------------------------------------------------------------------
__global__ __launch_bounds__(256) void compact_kernel(
    const int* __restrict__ eidx, int* __restrict__ counts, int* __restrict__ lists)
{
    const int s = blockIdx.x * 256 + threadIdx.x;
    const int e = eidx[s];
    const int pos = atomicAdd(&counts[e], 1);
    if (pos < LIST_CAP) lists[e * LIST_CAP + pos] = s;
}

// ---------------------------------------------------------------------------
// Kernel 2: FUSED expert FFN. grid (4 chunk-slots, 64 experts), 256 threads.
// Per 16-token chunk: stage x in LDS -> W1 pass (v kept in LDS) -> W2 pass
// -> score-scaled atomicAdd into out. No big intermediate in global: total
// workspace use is ~49 KB (metadata only).
// Phase 1: thread (colg=tid&63 -> float4 hidden col, tg1=tid>>6 -> 4 tokens).
// Phase 2: thread (colg2=tid&127 -> float4 out col, tg2=tid>>7 -> 8 tokens).
// LDS x/v reads are wave-uniform -> broadcast, conflict-free.
// ---------------------------------------------------------------------------
__global__ __launch_bounds__(256) void expert_fused_kernel(
    const float* __restrict__ x,
    const float* __restrict__ w1s, const float* __restrict__ b1s,
    const float* __restrict__ w2s, const float* __restrict__ b2s,
    const int* __restrict__ counts, const int* __restrict__ lists,
    const float* __restrict__ esc, float* __restrict__ out)
{
    __shared__ float xs[CHUNK * XPAD];   // 33.3 KB
    __shared__ float vs[CHUNK * VPAD];   // 16.9 KB
    __shared__ int   slotIds[CHUNK];
    const int e  = blockIdx.y;
    const int ne = min(counts[e], LIST_CAP);
    if (ne == 0) return;
    const int nChunks = (ne + CHUNK - 1) / CHUNK;
    const int tid = threadIdx.x;

    const float4* w1v = (const float4*)(w1s + (size_t)e * IN_W * BLOCK_H);
    const float4* w2v = (const float4*)(w2s + (size_t)e * BLOCK_H * OUT_W);
    const float4* x4  = (const float4*)x;

    const int colg  = tid & 63;        // phase-1 float4 col (256 hidden cols / 4)
    const int tg1   = tid >> 6;        // tokens tg1 + 4j
    const int colg2 = tid & 127;       // phase-2 float4 col (512 out cols / 4)
    const int tg2   = tid >> 7;        // tokens tg2 + 2j
    const float4 bias1 = ((const float4*)(b1s + (size_t)e * BLOCK_H))[colg];
    const float4 bias2 = ((const float4*)(b2s + (size_t)e * OUT_W))[colg2];

    for (int ci = blockIdx.x; ci < nChunks; ci += gridDim.x) {
        const int c0   = ci * CHUNK;
        const int nTok = min(CHUNK, ne - c0);
        if (tid < CHUNK) slotIds[tid] = (tid < nTok) ? lists[e * LIST_CAP + c0 + tid] : 0;
        __syncthreads();

        // stage token rows (zero-pad missing)
        for (int idx = tid; idx < CHUNK * 128; idx += 256) {
            const int t = idx >> 7, q = idx & 127;
            float4 v = make_float4(0.f, 0.f, 0.f, 0.f);
            if (t < nTok) v = x4[(size_t)(slotIds[t] >> 1) * 128 + q];
            *(float4*)&xs[t * XPAD + q * 4] = v;
        }
        __syncthreads();

        // ---- phase 1: v = relu(x @ W1 + b1) ----
        float4 a0 = make_float4(0.f,0.f,0.f,0.f), a1 = a0, a2 = a0, a3 = a0;
        #pragma unroll 4
        for (int i = 0; i < IN_W; ++i) {
            const float4 w = w1v[(size_t)i * 64 + colg];    // coalesced 1KB/wave
            const float x0 = xs[(tg1     ) * XPAD + i];     // wave-uniform broadcast
            const float x1 = xs[(tg1 +  4) * XPAD + i];
            const float x2 = xs[(tg1 +  8) * XPAD + i];
            const float x3 = xs[(tg1 + 12) * XPAD + i];
            a0.x = fmaf(x0,w.x,a0.x); a0.y = fmaf(x0,w.y,a0.y); a0.z = fmaf(x0,w.z,a0.z); a0.w = fmaf(x0,w.w,a0.w);
            a1.x = fmaf(x1,w.x,a1.x); a1.y = fmaf(x1,w.y,a1.y); a1.z = fmaf(x1,w.z,a1.z); a1.w = fmaf(x1,w.w,a1.w);
            a2.x = fmaf(x2,w.x,a2.x); a2.y = fmaf(x2,w.y,a2.y); a2.z = fmaf(x2,w.z,a2.z); a2.w = fmaf(x2,w.w,a2.w);
            a3.x = fmaf(x3,w.x,a3.x); a3.y = fmaf(x3,w.y,a3.y); a3.z = fmaf(x3,w.z,a3.z); a3.w = fmaf(x3,w.w,a3.w);
        }
        {
            float4 r;
            r.x=fmaxf(a0.x+bias1.x,0.f); r.y=fmaxf(a0.y+bias1.y,0.f); r.z=fmaxf(a0.z+bias1.z,0.f); r.w=fmaxf(a0.w+bias1.w,0.f);
            *(float4*)&vs[(tg1     ) * VPAD + colg*4] = r;
            r.x=fmaxf(a1.x+bias1.x,0.f); r.y=fmaxf(a1.y+bias1.y,0.f); r.z=fmaxf(a1.z+bias1.z,0.f); r.w=fmaxf(a1.w+bias1.w,0.f);
            *(float4*)&vs[(tg1 +  4) * VPAD + colg*4] = r;
            r.x=fmaxf(a2.x+bias1.x,0.f); r.y=fmaxf(a2.y+bias1.y,0.f); r.z=fmaxf(a2.z+bias1.z,0.f); r.w=fmaxf(a2.w+bias1.w,0.f);
            *(float4*)&vs[(tg1 +  8) * VPAD + colg*4] = r;
            r.x=fmaxf(a3.x+bias1.x,0.f); r.y=fmaxf(a3.y+bias1.y,0.f); r.z=fmaxf(a3.z+bias1.z,0.f); r.w=fmaxf(a3.w+bias1.w,0.f);
            *(float4*)&vs[(tg1 + 12) * VPAD + colg*4] = r;
        }
        __syncthreads();

        // ---- phase 2: out += score * (v @ W2 + b2) ----
        float4 b[8];
        #pragma unroll
        for (int j = 0; j < 8; ++j) b[j] = make_float4(0.f,0.f,0.f,0.f);
        #pragma unroll 2
        for (int h = 0; h < BLOCK_H; ++h) {
            const float4 w = w2v[(size_t)h * 128 + colg2];  // coalesced
            #pragma unroll
            for (int j = 0; j < 8; ++j) {
                const float vv = vs[(tg2 + 2*j) * VPAD + h];  // broadcast
                b[j].x = fmaf(vv,w.x,b[j].x); b[j].y = fmaf(vv,w.y,b[j].y);
                b[j].z = fmaf(vv,w.z,b[j].z); b[j].w = fmaf(vv,w.w,b[j].w);
            }
        }
        #pragma unroll
        for (int j = 0; j < 8; ++j) {
            const int t = tg2 + 2*j;
            if (t < nTok) {
                const int s   = slotIds[t];
                const float sc = esc[s];
                float* o = out + (size_t)(s >> 1) * OUT_W + colg2 * 4;
                atomicAdd(o + 0, (b[j].x + bias2.x) * sc);
                atomicAdd(o + 1, (b[j].y + bias2.y) * sc);
                atomicAdd(o + 2, (b[j].z + bias2.z) * sc);
                atomicAdd(o + 3, (b[j].w + bias2.w) * sc);
            }
        }
        __syncthreads();   // xs/vs/slotIds reused next chunk
    }
}

extern "C" void kernel_launch(void* const* d_in, const int* in_sizes, int n_in,
                              void* d_out, int out_size, void* d_ws, size_t ws_size,
                              hipStream_t stream) {
    const float* x      = (const float*)d_in[0];
    const float* noise  = (const float*)d_in[1];
    const float* w1s    = (const float*)d_in[2];
    const float* b1s    = (const float*)d_in[3];
    const float* w2s    = (const float*)d_in[4];
    const float* b2s    = (const float*)d_in[5];
    const float* mixer  = (const float*)d_in[6];
    const float* noisec = (const float*)d_in[7];
    float* out = (float*)d_out;

    // workspace layout — TOTAL ~49 KB (stay far under ws_size; round-2's 2.2 MB
    // layout overran d_ws and corrupted an adjacent allocation)
    char* ws = (char*)d_ws;
    int*   counts = (int*)ws;                                   ws += 256;
    int*   eidx   = (int*)ws;                                   ws += NSLOTS * sizeof(int);
    float* esc    = (float*)ws;                                 ws += NSLOTS * sizeof(float);
    int*   lists  = (int*)ws;   /* N_EXPERTS * LIST_CAP ints = 32 KB */

    hipMemsetAsync(d_out, 0, (size_t)out_size * sizeof(float), stream);
    hipMemsetAsync(counts, 0, 256, stream);

    routing_kernel<<<TOKENS / 8, 256, 0, stream>>>(x, noise, mixer, noisec, eidx, esc);
    compact_kernel<<<NSLOTS / 256, 256, 0, stream>>>(eidx, counts, lists);
    expert_fused_kernel<<<dim3(4, N_EXPERTS), 256, 0, stream>>>(
        x, w1s, b1s, w2s, b2s, counts, lists, esc, out);
}